// Round 6
// baseline (203.180 us; speedup 1.0000x reference)
//
#include <hip/hip_runtime.h>

#define NN 50000
#define NE 320000
#define FF 256
#define SCAN_B 196   // ceil(NN/256)

typedef short short8 __attribute__((ext_vector_type(8)));
typedef float f32x4 __attribute__((ext_vector_type(4)));
typedef unsigned short us4 __attribute__((ext_vector_type(4)));

static __device__ __forceinline__ unsigned short f2bf(float f) {
    union { float f; unsigned u; } v; v.f = f;
    unsigned r = v.u + 0x7FFFu + ((v.u >> 16) & 1u);   // RNE
    return (unsigned short)(r >> 16);
}

// ---------------- degree (int histogram over dst) ----------------
__global__ void k_deg(const int* __restrict__ ei, int* __restrict__ deg) {
    int e = blockIdx.x * blockDim.x + threadIdx.x;
    if (e < NE) atomicAdd(&deg[ei[NE + e]], 1);
}

// ---------------- hierarchical scan: block sums -> scan sums -> local scan ----------------
__global__ void k_scan1(const int* __restrict__ deg, int* __restrict__ bsum) {
    __shared__ int s[256];
    int i = blockIdx.x * 256 + threadIdx.x;
    s[threadIdx.x] = (i < NN) ? deg[i] : 0;
    __syncthreads();
    for (int d = 128; d > 0; d >>= 1) {
        if (threadIdx.x < d) s[threadIdx.x] += s[threadIdx.x + d];
        __syncthreads();
    }
    if (threadIdx.x == 0) bsum[blockIdx.x] = s[0];
}

__global__ void k_scan2(const int* __restrict__ bsum, int* __restrict__ boff) {
    __shared__ int s[256];
    int t = threadIdx.x;
    int v = (t < SCAN_B) ? bsum[t] : 0;
    s[t] = v;
    __syncthreads();
    for (int d = 1; d < 256; d <<= 1) {
        int u = (t >= d) ? s[t - d] : 0;
        __syncthreads();
        s[t] += u;
        __syncthreads();
    }
    if (t < SCAN_B) boff[t] = s[t] - v;
}

__global__ void k_scan3(const int* __restrict__ deg, const int* __restrict__ boff,
                        int* __restrict__ off, int* __restrict__ cur,
                        float* __restrict__ dinv) {
    __shared__ int s[256];
    int t = threadIdx.x;
    int i = blockIdx.x * 256 + t;
    int v = (i < NN) ? deg[i] : 0;
    s[t] = v;
    __syncthreads();
    for (int d = 1; d < 256; d <<= 1) {
        int u = (t >= d) ? s[t - d] : 0;
        __syncthreads();
        s[t] += u;
        __syncthreads();
    }
    if (i < NN) {
        int excl = boff[blockIdx.x] + s[t] - v;
        off[i] = excl;
        cur[i] = excl;
        dinv[i] = v > 0 ? rsqrtf((float)v) : 0.f;
    }
}

// ---------------- CSR fill ----------------
__global__ void k_fill(const int* __restrict__ ei, int* __restrict__ cur,
                       int* __restrict__ csr_src) {
    int e = blockIdx.x * blockDim.x + threadIdx.x;
    if (e < NE) {
        int dst = ei[NE + e];
        int pos = atomicAdd(&cur[dst], 1);
        csr_src[pos] = ei[e];
    }
}

// ---------------- aggregation (one wave/node) + fused x->bf16 conversion ----------------
__global__ __launch_bounds__(256)
void k_agg(const int* __restrict__ off, const int* __restrict__ deg,
           const int* __restrict__ csr_src, const float* __restrict__ dinv,
           const float* __restrict__ x, unsigned short* __restrict__ Ab) {
    int wid = (blockIdx.x * blockDim.x + threadIdx.x) >> 6;
    if (wid >= NN) return;
    int lane = threadIdx.x & 63;
    int start = off[wid];
    int d = deg[wid];
    float di = dinv[wid];
    float4 acc = make_float4(0.f, 0.f, 0.f, 0.f);
    int e = 0;
    for (; e + 2 <= d; e += 2) {
        int s0 = csr_src[start + e];
        int s1 = csr_src[start + e + 1];
        float w0 = di * dinv[s0];
        float w1 = di * dinv[s1];
        float4 v0 = *reinterpret_cast<const float4*>(&x[(size_t)s0 * FF + lane * 4]);
        float4 v1 = *reinterpret_cast<const float4*>(&x[(size_t)s1 * FF + lane * 4]);
        acc.x = fmaf(w0, v0.x, fmaf(w1, v1.x, acc.x));
        acc.y = fmaf(w0, v0.y, fmaf(w1, v1.y, acc.y));
        acc.z = fmaf(w0, v0.z, fmaf(w1, v1.z, acc.z));
        acc.w = fmaf(w0, v0.w, fmaf(w1, v1.w, acc.w));
    }
    if (e < d) {
        int s0 = csr_src[start + e];
        float w0 = di * dinv[s0];
        float4 v0 = *reinterpret_cast<const float4*>(&x[(size_t)s0 * FF + lane * 4]);
        acc.x = fmaf(w0, v0.x, acc.x);
        acc.y = fmaf(w0, v0.y, acc.y);
        acc.z = fmaf(w0, v0.z, acc.z);
        acc.w = fmaf(w0, v0.w, acc.w);
    }
    us4 o = {f2bf(acc.x), f2bf(acc.y), f2bf(acc.z), f2bf(acc.w)};
    *reinterpret_cast<us4*>(Ab + (size_t)wid * 512 + lane * 4) = o;
    // fused x->bf16: x-half (cols 256..511)
    float4 xv = *reinterpret_cast<const float4*>(&x[(size_t)wid * FF + lane * 4]);
    us4 ox = {f2bf(xv.x), f2bf(xv.y), f2bf(xv.z), f2bf(xv.w)};
    *reinterpret_cast<us4*>(Ab + (size_t)wid * 512 + 256 + lane * 4) = ox;
}

// ---------------- B prep: fragment-linear bf16 Bp [fb = kc*32+cf][lane][8] ----------------
__global__ void k_bprep(const float* __restrict__ wi, const float* __restrict__ wr,
                        unsigned short* __restrict__ Bp) {
    int t = blockIdx.x * blockDim.x + threadIdx.x;   // 0..32767
    int l = t & 63;
    int fb = t >> 6;          // 0..511
    int kc = fb >> 5;
    int cf = fb & 31;
    int col = cf * 16 + (l & 15);
    int kpart = col >> 8;
    int g = col & 255;
    int K0 = kc * 32 + (l >> 4) * 8;
    unsigned short* dst = Bp + (size_t)fb * 512 + (size_t)l * 8;
    #pragma unroll
    for (int e = 0; e < 8; ++e) {
        int K = K0 + e;
        const float* srcp = (K < 256) ? wi : wr;
        float v = srcp[(size_t)kpart * 65536 + (size_t)(K & 255) * 256 + g];
        dst[e] = f2bf(v);
    }
}

// ---------------- MFMA GEMM + epilogue, occupancy-optimized ----------------
// Block: 512 threads = 8 waves, 64 rows x 512 cols.
// Wave w owns cols [w*32, w*32+32) for k=0 and [256+w*32, 256+w*32+32) for k=1.
__global__ __launch_bounds__(512, 4)
void k_mm(const unsigned short* __restrict__ Ab, const unsigned short* __restrict__ Bp,
          const float* __restrict__ x, const float* __restrict__ bias,
          float* __restrict__ out) {
    const int l = threadIdx.x & 63;
    const int w = threadIdx.x >> 6;      // 0..7
    const int row0 = blockIdx.x * 64;
    const int rA = l & 15;
    const int kA = (l >> 4) * 8;

    f32x4 acc[4][4];                     // [row frag][c: 0,1=k0 cols, 2,3=k1 cols]
    #pragma unroll
    for (int i = 0; i < 4; ++i)
        #pragma unroll
        for (int j = 0; j < 4; ++j) acc[i][j] = (f32x4){0.f, 0.f, 0.f, 0.f};

    const unsigned short* ap[4];
    #pragma unroll
    for (int rf = 0; rf < 4; ++rf) {
        int r = row0 + rf * 16 + rA;
        if (r >= NN) r = NN - 1;         // clamp tail rows (stores masked below)
        ap[rf] = Ab + (size_t)r * 512 + kA;
    }
    const unsigned short* bp = Bp + (size_t)l * 8;

    #pragma unroll 1
    for (int kc = 0; kc < 16; ++kc) {
        short8 a[4], b[4];
        #pragma unroll
        for (int rf = 0; rf < 4; ++rf)
            a[rf] = *reinterpret_cast<const short8*>(ap[rf] + kc * 32);
        #pragma unroll
        for (int c = 0; c < 4; ++c) {
            int cf = (c < 2) ? (w * 2 + c) : (16 + w * 2 + (c - 2));
            b[c] = *reinterpret_cast<const short8*>(bp + (size_t)(kc * 32 + cf) * 512);
        }
        #pragma unroll
        for (int rf = 0; rf < 4; ++rf)
            #pragma unroll
            for (int c = 0; c < 4; ++c)
                acc[rf][c] = __builtin_amdgcn_mfma_f32_16x16x32_bf16(a[rf], b[c], acc[rf][c], 0, 0, 0);
    }

    __syncthreads();   // Ab aliases out: all waves' A reads must finish before stores

    #pragma unroll
    for (int rf = 0; rf < 4; ++rf) {
        const int rb = row0 + rf * 16 + (l >> 4) * 4;
        #pragma unroll
        for (int c = 0; c < 2; ++c) {
            const int gg = w * 32 + c * 16 + (l & 15);
            const float bv0 = bias[gg], bv1 = bias[256 + gg];
            #pragma unroll
            for (int j = 0; j < 4; ++j) {
                int r = rb + j;
                if (r < NN) {
                    float c0 = acc[rf][c][j] + bv0;
                    float c1 = acc[rf][c + 2][j] + bv1;
                    float arma = 0.5f * (fmaxf(c0, 0.f) + fmaxf(c1, 0.f));
                    out[(size_t)r * FF + gg] = x[(size_t)r * FF + gg] + fmaxf(arma, 0.f);
                }
            }
        }
    }
}

extern "C" void kernel_launch(void* const* d_in, const int* in_sizes, int n_in,
                              void* d_out, int out_size, void* d_ws, size_t ws_size,
                              hipStream_t stream) {
    const float* x    = (const float*)d_in[0];
    const int*   ei   = (const int*)d_in[1];
    const float* wi   = (const float*)d_in[2];
    const float* wr   = (const float*)d_in[3];
    const float* bias = (const float*)d_in[4];
    float* out = (float*)d_out;

    // workspace (~2.6 MB)
    int*   deg     = (int*)d_ws;              // NN
    int*   off     = deg + NN;                // NN
    int*   cur     = off + NN;                // NN
    int*   csr_src = cur + NN;                // NE
    float* dinv    = (float*)(csr_src + NE);  // NN
    int*   bsum    = (int*)(dinv + NN);       // SCAN_B
    int*   boff    = bsum + SCAN_B;           // SCAN_B
    unsigned short* Bp = (unsigned short*)(boff + SCAN_B);   // 512*512 bf16 = 512 KB
    unsigned short* Ab = (unsigned short*)d_out;             // 50000 x 512 bf16 == d_out bytes

    hipMemsetAsync(deg, 0, NN * sizeof(int), stream);

    k_deg  <<<(NE + 255) / 256, 256, 0, stream>>>(ei, deg);
    k_scan1<<<SCAN_B, 256, 0, stream>>>(deg, bsum);
    k_scan2<<<1, 256, 0, stream>>>(bsum, boff);
    k_scan3<<<SCAN_B, 256, 0, stream>>>(deg, boff, off, cur, dinv);
    k_fill <<<(NE + 255) / 256, 256, 0, stream>>>(ei, cur, csr_src);
    k_bprep<<<128, 256, 0, stream>>>(wi, wr, Bp);
    k_agg  <<<(NN * 64 + 255) / 256, 256, 0, stream>>>(off, deg, csr_src, dinv, x, Ab);
    k_mm   <<<(NN + 63) / 64, 512, 0, stream>>>(Ab, Bp, x, bias, out);
}

// Round 7
// 153.833 us; speedup vs baseline: 1.3208x; 1.3208x over previous
//
#include <hip/hip_runtime.h>

#define NN 50000
#define NE 320000
#define FF 256
#define SCAN_B 196   // ceil(NN/256)

typedef short short8 __attribute__((ext_vector_type(8)));
typedef float f32x4 __attribute__((ext_vector_type(4)));
typedef unsigned short us4 __attribute__((ext_vector_type(4)));

static __device__ __forceinline__ unsigned short f2bf(float f) {
    union { float f; unsigned u; } v; v.f = f;
    unsigned r = v.u + 0x7FFFu + ((v.u >> 16) & 1u);   // RNE
    return (unsigned short)(r >> 16);
}

// ---------------- degree (int histogram over dst) ----------------
__global__ void k_deg(const int* __restrict__ ei, int* __restrict__ deg) {
    int e = blockIdx.x * blockDim.x + threadIdx.x;
    if (e < NE) atomicAdd(&deg[ei[NE + e]], 1);
}

// ---------------- hierarchical scan: block sums -> scan sums -> local scan ----------------
__global__ void k_scan1(const int* __restrict__ deg, int* __restrict__ bsum) {
    __shared__ int s[256];
    int i = blockIdx.x * 256 + threadIdx.x;
    s[threadIdx.x] = (i < NN) ? deg[i] : 0;
    __syncthreads();
    for (int d = 128; d > 0; d >>= 1) {
        if (threadIdx.x < d) s[threadIdx.x] += s[threadIdx.x + d];
        __syncthreads();
    }
    if (threadIdx.x == 0) bsum[blockIdx.x] = s[0];
}

__global__ void k_scan2(const int* __restrict__ bsum, int* __restrict__ boff) {
    __shared__ int s[256];
    int t = threadIdx.x;
    int v = (t < SCAN_B) ? bsum[t] : 0;
    s[t] = v;
    __syncthreads();
    for (int d = 1; d < 256; d <<= 1) {
        int u = (t >= d) ? s[t - d] : 0;
        __syncthreads();
        s[t] += u;
        __syncthreads();
    }
    if (t < SCAN_B) boff[t] = s[t] - v;
}

__global__ void k_scan3(const int* __restrict__ deg, const int* __restrict__ boff,
                        int* __restrict__ off, int* __restrict__ cur,
                        float* __restrict__ dinv) {
    __shared__ int s[256];
    int t = threadIdx.x;
    int i = blockIdx.x * 256 + t;
    int v = (i < NN) ? deg[i] : 0;
    s[t] = v;
    __syncthreads();
    for (int d = 1; d < 256; d <<= 1) {
        int u = (t >= d) ? s[t - d] : 0;
        __syncthreads();
        s[t] += u;
        __syncthreads();
    }
    if (i < NN) {
        int excl = boff[blockIdx.x] + s[t] - v;
        off[i] = excl;
        cur[i] = excl;
        dinv[i] = v > 0 ? rsqrtf((float)v) : 0.f;
    }
}

// ---------------- CSR fill ----------------
__global__ void k_fill(const int* __restrict__ ei, int* __restrict__ cur,
                       int* __restrict__ csr_src) {
    int e = blockIdx.x * blockDim.x + threadIdx.x;
    if (e < NE) {
        int dst = ei[NE + e];
        int pos = atomicAdd(&cur[dst], 1);
        csr_src[pos] = ei[e];
    }
}

// ---------------- aggregation (one wave/node) + fused x->bf16, SWIZZLED Ab rows ----------
// Ab row byte layout: logical byte b stored at b ^ ((row&7)<<4).  Row-uniform XOR,
// so the wave's 512B stores stay coalesced.  k_mm copies rows verbatim into LDS via
// global_load_lds (linear dest) and un-swizzles at ds_read time (rule #21 pattern).
__global__ __launch_bounds__(256)
void k_agg(const int* __restrict__ off, const int* __restrict__ deg,
           const int* __restrict__ csr_src, const float* __restrict__ dinv,
           const float* __restrict__ x, unsigned short* __restrict__ Ab) {
    int wid = (blockIdx.x * blockDim.x + threadIdx.x) >> 6;
    if (wid >= NN) return;
    int lane = threadIdx.x & 63;
    int start = off[wid];
    int d = deg[wid];
    float di = dinv[wid];
    float4 acc = make_float4(0.f, 0.f, 0.f, 0.f);
    int e = 0;
    for (; e + 2 <= d; e += 2) {
        int s0 = csr_src[start + e];
        int s1 = csr_src[start + e + 1];
        float w0 = di * dinv[s0];
        float w1 = di * dinv[s1];
        float4 v0 = *reinterpret_cast<const float4*>(&x[(size_t)s0 * FF + lane * 4]);
        float4 v1 = *reinterpret_cast<const float4*>(&x[(size_t)s1 * FF + lane * 4]);
        acc.x = fmaf(w0, v0.x, fmaf(w1, v1.x, acc.x));
        acc.y = fmaf(w0, v0.y, fmaf(w1, v1.y, acc.y));
        acc.z = fmaf(w0, v0.z, fmaf(w1, v1.z, acc.z));
        acc.w = fmaf(w0, v0.w, fmaf(w1, v1.w, acc.w));
    }
    if (e < d) {
        int s0 = csr_src[start + e];
        float w0 = di * dinv[s0];
        float4 v0 = *reinterpret_cast<const float4*>(&x[(size_t)s0 * FF + lane * 4]);
        acc.x = fmaf(w0, v0.x, acc.x);
        acc.y = fmaf(w0, v0.y, acc.y);
        acc.z = fmaf(w0, v0.z, acc.z);
        acc.w = fmaf(w0, v0.w, acc.w);
    }
    char* rowp = (char*)(Ab + (size_t)wid * 512);
    const int sw = (wid & 7) << 4;
    us4 o = {f2bf(acc.x), f2bf(acc.y), f2bf(acc.z), f2bf(acc.w)};
    *reinterpret_cast<us4*>(rowp + ((lane * 8) ^ sw)) = o;
    // fused x->bf16: x-half (logical bytes 512..1023)
    float4 xv = *reinterpret_cast<const float4*>(&x[(size_t)wid * FF + lane * 4]);
    us4 ox = {f2bf(xv.x), f2bf(xv.y), f2bf(xv.z), f2bf(xv.w)};
    *reinterpret_cast<us4*>(rowp + ((512 + lane * 8) ^ sw)) = ox;
}

// ---------------- B prep: fragment-linear bf16 Bp [fb = kc*32+cf][lane][8] ----------------
__global__ void k_bprep(const float* __restrict__ wi, const float* __restrict__ wr,
                        unsigned short* __restrict__ Bp) {
    int t = blockIdx.x * blockDim.x + threadIdx.x;   // 0..32767
    int l = t & 63;
    int fb = t >> 6;          // 0..511
    int kc = fb >> 5;
    int cf = fb & 31;
    int col = cf * 16 + (l & 15);
    int kpart = col >> 8;
    int g = col & 255;
    int K0 = kc * 32 + (l >> 4) * 8;
    unsigned short* dst = Bp + (size_t)fb * 512 + (size_t)l * 8;
    #pragma unroll
    for (int e = 0; e < 8; ++e) {
        int K = K0 + e;
        const float* srcp = (K < 256) ? wi : wr;
        float v = srcp[(size_t)kpart * 65536 + (size_t)(K & 255) * 256 + g];
        dst[e] = f2bf(v);
    }
}

// ---------------- MFMA GEMM + epilogue, LDS-staged A panel ----------------
// Block: 512 threads = 8 waves, 64 rows x 512 cols.  A panel (64 x 512 bf16 = 64 KB)
// staged ONCE via global_load_lds (whole K), then barrier, then a barrier-free K-loop:
// per kc: 4 ds_read_b128 (swizzled) + 4 coalesced global B loads (L2) + 16 MFMA.
// Wave w owns cols [w*32, w*32+32) of k=0 and [256+w*32 ...) of k=1.
__global__ __launch_bounds__(512, 4)
void k_mm(const unsigned short* __restrict__ Ab, const unsigned short* __restrict__ Bp,
          const float* __restrict__ bias, float* __restrict__ out) {
    __shared__ char smem[65536];   // A panel, swizzled rows (1 KB each)

    const int l = threadIdx.x & 63;
    const int w = threadIdx.x >> 6;      // 0..7
    const int row0 = blockIdx.x * 64;

    // ---- stage: wave w copies rows {j*8 + w}, one 1KB row per global_load_lds round
    {
        const char* base = (const char*)Ab;
        #pragma unroll
        for (int j = 0; j < 8; ++j) {
            int rl = j * 8 + w;
            int rsrc = row0 + rl; if (rsrc >= NN) rsrc = NN - 1;   // clamp tail (masked later)
            const char* gp = base + (size_t)rsrc * 1024 + l * 16;
            __builtin_amdgcn_global_load_lds(
                (const __attribute__((address_space(1))) void*)gp,
                (__attribute__((address_space(3))) void*)(smem + rl * 1024),
                16, 0, 0);
        }
    }
    __syncthreads();

    f32x4 acc[4][4];                     // [row frag][c: 0,1=k0 cols, 2,3=k1 cols]
    #pragma unroll
    for (int i = 0; i < 4; ++i)
        #pragma unroll
        for (int j = 0; j < 4; ++j) acc[i][j] = (f32x4){0.f, 0.f, 0.f, 0.f};

    const unsigned short* bp = Bp + (size_t)l * 8;
    const int swl = (l & 7) << 4;        // row-parity XOR for this lane's frag rows
    const int cbase = (l >> 4) * 16;     // 16B sub-column per lane quarter

    #pragma unroll 1
    for (int kc = 0; kc < 16; ++kc) {
        short8 a[4], b[4];
        #pragma unroll
        for (int rf = 0; rf < 4; ++rf) {
            int rl = rf * 16 + (l & 15);
            int addr = rl * 1024 + ((kc * 64 + cbase) ^ swl);
            a[rf] = *reinterpret_cast<const short8*>(&smem[addr]);
        }
        #pragma unroll
        for (int c = 0; c < 4; ++c) {
            int cf = (c < 2) ? (w * 2 + c) : (16 + w * 2 + (c - 2));
            b[c] = *reinterpret_cast<const short8*>(bp + (size_t)(kc * 32 + cf) * 512);
        }
        #pragma unroll
        for (int rf = 0; rf < 4; ++rf)
            #pragma unroll
            for (int c = 0; c < 4; ++c)
                acc[rf][c] = __builtin_amdgcn_mfma_f32_16x16x32_bf16(a[rf], b[c], acc[rf][c], 0, 0, 0);
    }

    // ---- epilogue: residual x read as bf16 from the LDS x-half (saves 50 MB HBM)
    #pragma unroll
    for (int rf = 0; rf < 4; ++rf) {
        const int rl0 = rf * 16 + (l >> 4) * 4;
        #pragma unroll
        for (int j = 0; j < 4; ++j) {
            int rl = rl0 + j;
            int r = row0 + rl;
            if (r >= NN) continue;
            int sw = (rl & 7) << 4;
            #pragma unroll
            for (int c = 0; c < 2; ++c) {
                int gg = w * 32 + c * 16 + (l & 15);
                unsigned short xb =
                    *reinterpret_cast<const unsigned short*>(&smem[rl * 1024 + ((512 + gg * 2) ^ sw)]);
                float xv = __uint_as_float((unsigned)xb << 16);
                float c0 = acc[rf][c][j] + bias[gg];
                float c1 = acc[rf][c + 2][j] + bias[256 + gg];
                float arma = 0.5f * (fmaxf(c0, 0.f) + fmaxf(c1, 0.f));
                out[(size_t)r * FF + gg] = xv + fmaxf(arma, 0.f);
            }
        }
    }
}

extern "C" void kernel_launch(void* const* d_in, const int* in_sizes, int n_in,
                              void* d_out, int out_size, void* d_ws, size_t ws_size,
                              hipStream_t stream) {
    const float* x    = (const float*)d_in[0];
    const int*   ei   = (const int*)d_in[1];
    const float* wi   = (const float*)d_in[2];
    const float* wr   = (const float*)d_in[3];
    const float* bias = (const float*)d_in[4];
    float* out = (float*)d_out;

    // workspace (~2.6 MB)
    int*   deg     = (int*)d_ws;              // NN
    int*   off     = deg + NN;                // NN
    int*   cur     = off + NN;                // NN
    int*   csr_src = cur + NN;                // NE
    float* dinv    = (float*)(csr_src + NE);  // NN
    int*   bsum    = (int*)(dinv + NN);       // SCAN_B
    int*   boff    = bsum + SCAN_B;           // SCAN_B
    unsigned short* Bp = (unsigned short*)(boff + SCAN_B);   // 512*512 bf16 = 512 KB
    unsigned short* Ab = (unsigned short*)d_out;             // 50000 x 512 bf16 == d_out bytes

    hipMemsetAsync(deg, 0, NN * sizeof(int), stream);

    k_deg  <<<(NE + 255) / 256, 256, 0, stream>>>(ei, deg);
    k_scan1<<<SCAN_B, 256, 0, stream>>>(deg, bsum);
    k_scan2<<<1, 256, 0, stream>>>(bsum, boff);
    k_scan3<<<SCAN_B, 256, 0, stream>>>(deg, boff, off, cur, dinv);
    k_fill <<<(NE + 255) / 256, 256, 0, stream>>>(ei, cur, csr_src);
    k_bprep<<<128, 256, 0, stream>>>(wi, wr, Bp);
    k_agg  <<<(NN * 64 + 255) / 256, 256, 0, stream>>>(off, deg, csr_src, dinv, x, Ab);
    k_mm   <<<(NN + 63) / 64, 512, 0, stream>>>(Ab, Bp, bias, out);
}

// Round 8
// 136.909 us; speedup vs baseline: 1.4840x; 1.1236x over previous
//
#include <hip/hip_runtime.h>

#define NN 50000
#define NE 320000
#define FF 256
#define SCAN_B 196   // ceil(NN/256)

typedef short short8 __attribute__((ext_vector_type(8)));
typedef float f32x4 __attribute__((ext_vector_type(4)));
typedef unsigned short us4 __attribute__((ext_vector_type(4)));

static __device__ __forceinline__ unsigned short f2bf(float f) {
    union { float f; unsigned u; } v; v.f = f;
    unsigned r = v.u + 0x7FFFu + ((v.u >> 16) & 1u);   // RNE
    return (unsigned short)(r >> 16);
}
static __device__ __forceinline__ float bf2f(unsigned short h) {
    return __uint_as_float((unsigned)h << 16);
}

// ---------------- degree (int histogram over dst) ----------------
__global__ void k_deg(const int* __restrict__ ei, int* __restrict__ deg) {
    int e = blockIdx.x * blockDim.x + threadIdx.x;
    if (e < NE) atomicAdd(&deg[ei[NE + e]], 1);
}

// ---------------- hierarchical scan ----------------
__global__ void k_scan1(const int* __restrict__ deg, int* __restrict__ bsum) {
    __shared__ int s[256];
    int i = blockIdx.x * 256 + threadIdx.x;
    s[threadIdx.x] = (i < NN) ? deg[i] : 0;
    __syncthreads();
    for (int d = 128; d > 0; d >>= 1) {
        if (threadIdx.x < d) s[threadIdx.x] += s[threadIdx.x + d];
        __syncthreads();
    }
    if (threadIdx.x == 0) bsum[blockIdx.x] = s[0];
}

__global__ void k_scan2(const int* __restrict__ bsum, int* __restrict__ boff) {
    __shared__ int s[256];
    int t = threadIdx.x;
    int v = (t < SCAN_B) ? bsum[t] : 0;
    s[t] = v;
    __syncthreads();
    for (int d = 1; d < 256; d <<= 1) {
        int u = (t >= d) ? s[t - d] : 0;
        __syncthreads();
        s[t] += u;
        __syncthreads();
    }
    if (t < SCAN_B) boff[t] = s[t] - v;
}

__global__ void k_scan3(const int* __restrict__ deg, const int* __restrict__ boff,
                        int* __restrict__ off, int* __restrict__ cur,
                        float* __restrict__ dinv) {
    __shared__ int s[256];
    int t = threadIdx.x;
    int i = blockIdx.x * 256 + t;
    int v = (i < NN) ? deg[i] : 0;
    s[t] = v;
    __syncthreads();
    for (int d = 1; d < 256; d <<= 1) {
        int u = (t >= d) ? s[t - d] : 0;
        __syncthreads();
        s[t] += u;
        __syncthreads();
    }
    if (i < NN) {
        int excl = boff[blockIdx.x] + s[t] - v;
        off[i] = excl;
        cur[i] = excl;
        dinv[i] = v > 0 ? rsqrtf((float)v) : 0.f;
    }
}

// ---------------- CSR fill ----------------
__global__ void k_fill(const int* __restrict__ ei, int* __restrict__ cur,
                       int* __restrict__ csr_src) {
    int e = blockIdx.x * blockDim.x + threadIdx.x;
    if (e < NE) {
        int dst = ei[NE + e];
        int pos = atomicAdd(&cur[dst], 1);
        csr_src[pos] = ei[e];
    }
}

// ---------------- x -> bf16 x-half of Ab (swizzled rows), runs BEFORE k_agg ----------
// Ab row byte layout: logical byte b stored at b ^ ((row&7)<<4).
__global__ void k_xcvt(const float* __restrict__ x, unsigned short* __restrict__ Ab) {
    int t = blockIdx.x * blockDim.x + threadIdx.x;
    if (t >= NN * 64) return;
    int n = t >> 6, q = t & 63;
    float4 v = *reinterpret_cast<const float4*>(&x[(size_t)n * FF + q * 4]);
    us4 o = {f2bf(v.x), f2bf(v.y), f2bf(v.z), f2bf(v.w)};
    char* rowp = (char*)(Ab + (size_t)n * 512);
    *reinterpret_cast<us4*>(rowp + ((512 + q * 8) ^ ((n & 7) << 4))) = o;
}

// ---------------- aggregation: gather BF16 x rows from Ab x-half, write y-half ------
// Reads Ab[src] x-half (written by k_xcvt), writes Ab[wid] y-half. No overlap -> no race.
__global__ __launch_bounds__(256)
void k_agg(const int* __restrict__ off, const int* __restrict__ deg,
           const int* __restrict__ csr_src, const float* __restrict__ dinv,
           unsigned short* __restrict__ Ab) {
    int wid = (blockIdx.x * blockDim.x + threadIdx.x) >> 6;
    if (wid >= NN) return;
    int lane = threadIdx.x & 63;
    int start = off[wid];
    int d = deg[wid];
    float di = dinv[wid];
    const char* base = (const char*)Ab;
    const int lb = 512 + lane * 8;       // logical byte offset of this lane's 4 bf16 in x-half
    float4 acc = make_float4(0.f, 0.f, 0.f, 0.f);
    int e = 0;
    for (; e + 4 <= d; e += 4) {
        int s0 = csr_src[start + e + 0];
        int s1 = csr_src[start + e + 1];
        int s2 = csr_src[start + e + 2];
        int s3 = csr_src[start + e + 3];
        us4 v0 = *reinterpret_cast<const us4*>(base + (size_t)s0 * 1024 + (lb ^ ((s0 & 7) << 4)));
        us4 v1 = *reinterpret_cast<const us4*>(base + (size_t)s1 * 1024 + (lb ^ ((s1 & 7) << 4)));
        us4 v2 = *reinterpret_cast<const us4*>(base + (size_t)s2 * 1024 + (lb ^ ((s2 & 7) << 4)));
        us4 v3 = *reinterpret_cast<const us4*>(base + (size_t)s3 * 1024 + (lb ^ ((s3 & 7) << 4)));
        float w0 = di * dinv[s0], w1 = di * dinv[s1], w2 = di * dinv[s2], w3 = di * dinv[s3];
        acc.x = fmaf(w0, bf2f(v0[0]), fmaf(w1, bf2f(v1[0]), fmaf(w2, bf2f(v2[0]), fmaf(w3, bf2f(v3[0]), acc.x))));
        acc.y = fmaf(w0, bf2f(v0[1]), fmaf(w1, bf2f(v1[1]), fmaf(w2, bf2f(v2[1]), fmaf(w3, bf2f(v3[1]), acc.y))));
        acc.z = fmaf(w0, bf2f(v0[2]), fmaf(w1, bf2f(v1[2]), fmaf(w2, bf2f(v2[2]), fmaf(w3, bf2f(v3[2]), acc.z))));
        acc.w = fmaf(w0, bf2f(v0[3]), fmaf(w1, bf2f(v1[3]), fmaf(w2, bf2f(v2[3]), fmaf(w3, bf2f(v3[3]), acc.w))));
    }
    for (; e < d; ++e) {
        int s0 = csr_src[start + e];
        us4 v0 = *reinterpret_cast<const us4*>(base + (size_t)s0 * 1024 + (lb ^ ((s0 & 7) << 4)));
        float w0 = di * dinv[s0];
        acc.x = fmaf(w0, bf2f(v0[0]), acc.x);
        acc.y = fmaf(w0, bf2f(v0[1]), acc.y);
        acc.z = fmaf(w0, bf2f(v0[2]), acc.z);
        acc.w = fmaf(w0, bf2f(v0[3]), acc.w);
    }
    char* rowp = (char*)(Ab + (size_t)wid * 512);
    us4 o = {f2bf(acc.x), f2bf(acc.y), f2bf(acc.z), f2bf(acc.w)};
    *reinterpret_cast<us4*>(rowp + ((lane * 8) ^ ((wid & 7) << 4))) = o;
}

// ---------------- B prep: fragment-linear bf16 Bp [fb = kc*32+cf][lane][8] ----------------
__global__ void k_bprep(const float* __restrict__ wi, const float* __restrict__ wr,
                        unsigned short* __restrict__ Bp) {
    int t = blockIdx.x * blockDim.x + threadIdx.x;   // 0..32767
    int l = t & 63;
    int fb = t >> 6;          // 0..511
    int kc = fb >> 5;
    int cf = fb & 31;
    int col = cf * 16 + (l & 15);
    int kpart = col >> 8;
    int g = col & 255;
    int K0 = kc * 32 + (l >> 4) * 8;
    unsigned short* dst = Bp + (size_t)fb * 512 + (size_t)l * 8;
    #pragma unroll
    for (int e = 0; e < 8; ++e) {
        int K = K0 + e;
        const float* srcp = (K < 256) ? wi : wr;
        float v = srcp[(size_t)kpart * 65536 + (size_t)(K & 255) * 256 + g];
        dst[e] = f2bf(v);
    }
}

// ---------------- MFMA GEMM + epilogue, LDS-staged A panel ----------------
__global__ __launch_bounds__(512, 4)
void k_mm(const unsigned short* __restrict__ Ab, const unsigned short* __restrict__ Bp,
          const float* __restrict__ bias, float* __restrict__ out) {
    __shared__ char smem[65536];   // A panel, swizzled rows (1 KB each)

    const int l = threadIdx.x & 63;
    const int w = threadIdx.x >> 6;      // 0..7
    const int row0 = blockIdx.x * 64;

    // ---- stage: wave w copies rows {j*8 + w}, one 1KB row per global_load_lds round
    {
        const char* base = (const char*)Ab;
        #pragma unroll
        for (int j = 0; j < 8; ++j) {
            int rl = j * 8 + w;
            int rsrc = row0 + rl; if (rsrc >= NN) rsrc = NN - 1;   // clamp tail (masked later)
            const char* gp = base + (size_t)rsrc * 1024 + l * 16;
            __builtin_amdgcn_global_load_lds(
                (const __attribute__((address_space(1))) void*)gp,
                (__attribute__((address_space(3))) void*)(smem + rl * 1024),
                16, 0, 0);
        }
    }
    __syncthreads();

    f32x4 acc[4][4];                     // [row frag][c: 0,1=k0 cols, 2,3=k1 cols]
    #pragma unroll
    for (int i = 0; i < 4; ++i)
        #pragma unroll
        for (int j = 0; j < 4; ++j) acc[i][j] = (f32x4){0.f, 0.f, 0.f, 0.f};

    const unsigned short* bp = Bp + (size_t)l * 8;
    const int swl = (l & 7) << 4;        // row-parity XOR for this lane's frag rows
    const int cbase = (l >> 4) * 16;     // 16B sub-column per lane quarter

    #pragma unroll 1
    for (int kc = 0; kc < 16; ++kc) {
        short8 a[4], b[4];
        #pragma unroll
        for (int rf = 0; rf < 4; ++rf) {
            int rl = rf * 16 + (l & 15);
            int addr = rl * 1024 + ((kc * 64 + cbase) ^ swl);
            a[rf] = *reinterpret_cast<const short8*>(&smem[addr]);
        }
        #pragma unroll
        for (int c = 0; c < 4; ++c) {
            int cf = (c < 2) ? (w * 2 + c) : (16 + w * 2 + (c - 2));
            b[c] = *reinterpret_cast<const short8*>(bp + (size_t)(kc * 32 + cf) * 512);
        }
        #pragma unroll
        for (int rf = 0; rf < 4; ++rf)
            #pragma unroll
            for (int c = 0; c < 4; ++c)
                acc[rf][c] = __builtin_amdgcn_mfma_f32_16x16x32_bf16(a[rf], b[c], acc[rf][c], 0, 0, 0);
    }

    // ---- epilogue: residual x read as bf16 from the LDS x-half
    #pragma unroll
    for (int rf = 0; rf < 4; ++rf) {
        const int rl0 = rf * 16 + (l >> 4) * 4;
        #pragma unroll
        for (int j = 0; j < 4; ++j) {
            int rl = rl0 + j;
            int r = row0 + rl;
            if (r >= NN) continue;
            int sw = (rl & 7) << 4;
            #pragma unroll
            for (int c = 0; c < 2; ++c) {
                int gg = w * 32 + c * 16 + (l & 15);
                unsigned short xb =
                    *reinterpret_cast<const unsigned short*>(&smem[rl * 1024 + ((512 + gg * 2) ^ sw)]);
                float xv = bf2f(xb);
                float c0 = acc[rf][c][j] + bias[gg];
                float c1 = acc[rf][c + 2][j] + bias[256 + gg];
                float arma = 0.5f * (fmaxf(c0, 0.f) + fmaxf(c1, 0.f));
                out[(size_t)r * FF + gg] = xv + fmaxf(arma, 0.f);
            }
        }
    }
}

extern "C" void kernel_launch(void* const* d_in, const int* in_sizes, int n_in,
                              void* d_out, int out_size, void* d_ws, size_t ws_size,
                              hipStream_t stream) {
    const float* x    = (const float*)d_in[0];
    const int*   ei   = (const int*)d_in[1];
    const float* wi   = (const float*)d_in[2];
    const float* wr   = (const float*)d_in[3];
    const float* bias = (const float*)d_in[4];
    float* out = (float*)d_out;

    // workspace (~2.6 MB)
    int*   deg     = (int*)d_ws;              // NN
    int*   off     = deg + NN;                // NN
    int*   cur     = off + NN;                // NN
    int*   csr_src = cur + NN;                // NE
    float* dinv    = (float*)(csr_src + NE);  // NN
    int*   bsum    = (int*)(dinv + NN);       // SCAN_B
    int*   boff    = bsum + SCAN_B;           // SCAN_B
    unsigned short* Bp = (unsigned short*)(boff + SCAN_B);   // 512*512 bf16 = 512 KB
    unsigned short* Ab = (unsigned short*)d_out;             // 50000 x 512 bf16 == d_out bytes

    hipMemsetAsync(deg, 0, NN * sizeof(int), stream);

    k_deg  <<<(NE + 255) / 256, 256, 0, stream>>>(ei, deg);
    k_scan1<<<SCAN_B, 256, 0, stream>>>(deg, bsum);
    k_scan2<<<1, 256, 0, stream>>>(bsum, boff);
    k_scan3<<<SCAN_B, 256, 0, stream>>>(deg, boff, off, cur, dinv);
    k_fill <<<(NE + 255) / 256, 256, 0, stream>>>(ei, cur, csr_src);
    k_xcvt <<<(NN * 64 + 255) / 256, 256, 0, stream>>>(x, Ab);
    k_bprep<<<128, 256, 0, stream>>>(wi, wr, Bp);
    k_agg  <<<(NN * 64 + 255) / 256, 256, 0, stream>>>(off, deg, csr_src, dinv, Ab);
    k_mm   <<<(NN + 63) / 64, 512, 0, stream>>>(Ab, Bp, bias, out);
}

// Round 9
// 135.897 us; speedup vs baseline: 1.4951x; 1.0074x over previous
//
#include <hip/hip_runtime.h>

#define NN 50000
#define NE 320000
#define FF 256
#define SCAN_B 196   // ceil(NN/256)

typedef short short8 __attribute__((ext_vector_type(8)));
typedef float f32x4 __attribute__((ext_vector_type(4)));
typedef unsigned short us4 __attribute__((ext_vector_type(4)));

static __device__ __forceinline__ unsigned short f2bf(float f) {
    union { float f; unsigned u; } v; v.f = f;
    unsigned r = v.u + 0x7FFFu + ((v.u >> 16) & 1u);   // RNE
    return (unsigned short)(r >> 16);
}
static __device__ __forceinline__ float bf2f(unsigned short h) {
    return __uint_as_float((unsigned)h << 16);
}

// ---------------- degree (int histogram over dst) ----------------
__global__ void k_deg(const int* __restrict__ ei, int* __restrict__ deg) {
    int e = blockIdx.x * blockDim.x + threadIdx.x;
    if (e < NE) atomicAdd(&deg[ei[NE + e]], 1);
}

// ---------------- hierarchical scan ----------------
__global__ void k_scan1(const int* __restrict__ deg, int* __restrict__ bsum) {
    __shared__ int s[256];
    int i = blockIdx.x * 256 + threadIdx.x;
    s[threadIdx.x] = (i < NN) ? deg[i] : 0;
    __syncthreads();
    for (int d = 128; d > 0; d >>= 1) {
        if (threadIdx.x < d) s[threadIdx.x] += s[threadIdx.x + d];
        __syncthreads();
    }
    if (threadIdx.x == 0) bsum[blockIdx.x] = s[0];
}

__global__ void k_scan2(const int* __restrict__ bsum, int* __restrict__ boff) {
    __shared__ int s[256];
    int t = threadIdx.x;
    int v = (t < SCAN_B) ? bsum[t] : 0;
    s[t] = v;
    __syncthreads();
    for (int d = 1; d < 256; d <<= 1) {
        int u = (t >= d) ? s[t - d] : 0;
        __syncthreads();
        s[t] += u;
        __syncthreads();
    }
    if (t < SCAN_B) boff[t] = s[t] - v;
}

__global__ void k_scan3(const int* __restrict__ deg, const int* __restrict__ boff,
                        int* __restrict__ off, int* __restrict__ cur,
                        float* __restrict__ dinv) {
    __shared__ int s[256];
    int t = threadIdx.x;
    int i = blockIdx.x * 256 + t;
    int v = (i < NN) ? deg[i] : 0;
    s[t] = v;
    __syncthreads();
    for (int d = 1; d < 256; d <<= 1) {
        int u = (t >= d) ? s[t - d] : 0;
        __syncthreads();
        s[t] += u;
        __syncthreads();
    }
    if (i < NN) {
        int excl = boff[blockIdx.x] + s[t] - v;
        off[i] = excl;
        cur[i] = excl;
        dinv[i] = v > 0 ? rsqrtf((float)v) : 0.f;
    }
}

// ---------------- CSR fill ----------------
__global__ void k_fill(const int* __restrict__ ei, int* __restrict__ cur,
                       int* __restrict__ csr_src) {
    int e = blockIdx.x * blockDim.x + threadIdx.x;
    if (e < NE) {
        int dst = ei[NE + e];
        int pos = atomicAdd(&cur[dst], 1);
        csr_src[pos] = ei[e];
    }
}

// ---------------- x -> bf16 x-half of Ab (swizzled rows), runs BEFORE k_agg ----------
// Ab row byte layout: logical byte b stored at b ^ ((row&7)<<4).
__global__ void k_xcvt(const float* __restrict__ x, unsigned short* __restrict__ Ab) {
    int t = blockIdx.x * blockDim.x + threadIdx.x;
    if (t >= NN * 64) return;
    int n = t >> 6, q = t & 63;
    float4 v = *reinterpret_cast<const float4*>(&x[(size_t)n * FF + q * 4]);
    us4 o = {f2bf(v.x), f2bf(v.y), f2bf(v.z), f2bf(v.w)};
    char* rowp = (char*)(Ab + (size_t)n * 512);
    *reinterpret_cast<us4*>(rowp + ((512 + q * 8) ^ ((n & 7) << 4))) = o;
}

// ---------------- aggregation: gather BF16 x rows from Ab x-half, write y-half ------
__global__ __launch_bounds__(256)
void k_agg(const int* __restrict__ off, const int* __restrict__ deg,
           const int* __restrict__ csr_src, const float* __restrict__ dinv,
           unsigned short* __restrict__ Ab) {
    int wid = (blockIdx.x * blockDim.x + threadIdx.x) >> 6;
    if (wid >= NN) return;
    int lane = threadIdx.x & 63;
    int start = off[wid];
    int d = deg[wid];
    float di = dinv[wid];
    const char* base = (const char*)Ab;
    const int lb = 512 + lane * 8;       // logical byte offset of this lane's 4 bf16 in x-half
    float4 acc = make_float4(0.f, 0.f, 0.f, 0.f);
    int e = 0;
    for (; e + 4 <= d; e += 4) {
        int s0 = csr_src[start + e + 0];
        int s1 = csr_src[start + e + 1];
        int s2 = csr_src[start + e + 2];
        int s3 = csr_src[start + e + 3];
        us4 v0 = *reinterpret_cast<const us4*>(base + (size_t)s0 * 1024 + (lb ^ ((s0 & 7) << 4)));
        us4 v1 = *reinterpret_cast<const us4*>(base + (size_t)s1 * 1024 + (lb ^ ((s1 & 7) << 4)));
        us4 v2 = *reinterpret_cast<const us4*>(base + (size_t)s2 * 1024 + (lb ^ ((s2 & 7) << 4)));
        us4 v3 = *reinterpret_cast<const us4*>(base + (size_t)s3 * 1024 + (lb ^ ((s3 & 7) << 4)));
        float w0 = di * dinv[s0], w1 = di * dinv[s1], w2 = di * dinv[s2], w3 = di * dinv[s3];
        acc.x = fmaf(w0, bf2f(v0[0]), fmaf(w1, bf2f(v1[0]), fmaf(w2, bf2f(v2[0]), fmaf(w3, bf2f(v3[0]), acc.x))));
        acc.y = fmaf(w0, bf2f(v0[1]), fmaf(w1, bf2f(v1[1]), fmaf(w2, bf2f(v2[1]), fmaf(w3, bf2f(v3[1]), acc.y))));
        acc.z = fmaf(w0, bf2f(v0[2]), fmaf(w1, bf2f(v1[2]), fmaf(w2, bf2f(v2[2]), fmaf(w3, bf2f(v3[2]), acc.z))));
        acc.w = fmaf(w0, bf2f(v0[3]), fmaf(w1, bf2f(v1[3]), fmaf(w2, bf2f(v2[3]), fmaf(w3, bf2f(v3[3]), acc.w))));
    }
    for (; e < d; ++e) {
        int s0 = csr_src[start + e];
        us4 v0 = *reinterpret_cast<const us4*>(base + (size_t)s0 * 1024 + (lb ^ ((s0 & 7) << 4)));
        float w0 = di * dinv[s0];
        acc.x = fmaf(w0, bf2f(v0[0]), acc.x);
        acc.y = fmaf(w0, bf2f(v0[1]), acc.y);
        acc.z = fmaf(w0, bf2f(v0[2]), acc.z);
        acc.w = fmaf(w0, bf2f(v0[3]), acc.w);
    }
    char* rowp = (char*)(Ab + (size_t)wid * 512);
    us4 o = {f2bf(acc.x), f2bf(acc.y), f2bf(acc.z), f2bf(acc.w)};
    *reinterpret_cast<us4*>(rowp + ((lane * 8) ^ ((wid & 7) << 4))) = o;
}

// ---------------- B prep: fragment-linear bf16 Bp [fb = kc*32+cf][lane][8] ----------------
__global__ void k_bprep(const float* __restrict__ wi, const float* __restrict__ wr,
                        unsigned short* __restrict__ Bp) {
    int t = blockIdx.x * blockDim.x + threadIdx.x;   // 0..32767
    int l = t & 63;
    int fb = t >> 6;          // 0..511
    int kc = fb >> 5;
    int cf = fb & 31;
    int col = cf * 16 + (l & 15);
    int kpart = col >> 8;
    int g = col & 255;
    int K0 = kc * 32 + (l >> 4) * 8;
    unsigned short* dst = Bp + (size_t)fb * 512 + (size_t)l * 8;
    #pragma unroll
    for (int e = 0; e < 8; ++e) {
        int K = K0 + e;
        const float* srcp = (K < 256) ? wi : wr;
        float v = srcp[(size_t)kpart * 65536 + (size_t)(K & 255) * 256 + g];
        dst[e] = f2bf(v);
    }
}

// ---------------- MFMA GEMM + epilogue, LDS A panel + B register ping-pong --------
// Block: 512 threads = 8 waves, 64 rows x 512 cols.  A panel staged once (64 KB).
// K-loop: no barriers; B frags for kc+1 issued before MFMAs of kc (counted vmcnt).
#define LOADB(dst, kc_)                                                           \
    {                                                                             \
        dst[0] = *reinterpret_cast<const short8*>(bpb + (kc_) * 32768 + (2 * w + 0) * 1024);        \
        dst[1] = *reinterpret_cast<const short8*>(bpb + (kc_) * 32768 + (2 * w + 1) * 1024);        \
        dst[2] = *reinterpret_cast<const short8*>(bpb + (kc_) * 32768 + (16 + 2 * w) * 1024);       \
        dst[3] = *reinterpret_cast<const short8*>(bpb + (kc_) * 32768 + (17 + 2 * w) * 1024);       \
    }
#define LOADA(dst, ab, kc2_)                                                      \
    {                                                                             \
        _Pragma("unroll")                                                         \
        for (int rf = 0; rf < 4; ++rf)                                            \
            dst[rf] = *reinterpret_cast<const short8*>(ab + rf * 16384 + (kc2_) * 128); \
    }
#define MFMA4(aset, bset)                                                         \
    {                                                                             \
        _Pragma("unroll")                                                         \
        for (int rf = 0; rf < 4; ++rf)                                            \
            _Pragma("unroll")                                                     \
            for (int c = 0; c < 4; ++c)                                           \
                acc[rf][c] = __builtin_amdgcn_mfma_f32_16x16x32_bf16(aset[rf], bset[c], acc[rf][c], 0, 0, 0); \
    }

__global__ __launch_bounds__(512, 4)
void k_mm(const unsigned short* __restrict__ Ab, const unsigned short* __restrict__ Bp,
          const float* __restrict__ bias, float* __restrict__ out) {
    __shared__ char smem[65536];   // A panel, swizzled rows (1 KB each)

    const int l = threadIdx.x & 63;
    const int w = threadIdx.x >> 6;      // 0..7
    const int row0 = blockIdx.x * 64;

    // ---- stage: wave w copies rows {j*8 + w}, one 1KB row per global_load_lds round
    {
        const char* base = (const char*)Ab;
        #pragma unroll
        for (int j = 0; j < 8; ++j) {
            int rl = j * 8 + w;
            int rsrc = row0 + rl; if (rsrc >= NN) rsrc = NN - 1;   // clamp tail (masked later)
            const char* gp = base + (size_t)rsrc * 1024 + l * 16;
            __builtin_amdgcn_global_load_lds(
                (const __attribute__((address_space(1))) void*)gp,
                (__attribute__((address_space(3))) void*)(smem + rl * 1024),
                16, 0, 0);
        }
    }
    __syncthreads();

    f32x4 acc[4][4];                     // [row frag][c: 0,1=k0 cols, 2,3=k1 cols]
    #pragma unroll
    for (int i = 0; i < 4; ++i)
        #pragma unroll
        for (int j = 0; j < 4; ++j) acc[i][j] = (f32x4){0.f, 0.f, 0.f, 0.f};

    // per-lane invariant A base (even kc); odd kc = base ^ 64.
    // addr(rf,kc) = (l&15)*1024 + rf*16384 + (kc>>1)*128
    //             + (((kc&1)^(p>>2))<<6) + ((q^(p&3))<<4),  p=l&7, q=l>>4
    const int p = l & 7, q = l >> 4;
    const char* abase0 = smem + (l & 15) * 1024 + ((p >> 2) << 6) + ((q ^ (p & 3)) << 4);
    const char* abase1 = smem + (((size_t)(abase0 - smem)) ^ 64);
    const char* bpb = (const char*)(Bp + (size_t)l * 8);

    short8 b0[4], b1[4], a[4];
    LOADB(b0, 0)
    #pragma unroll 1
    for (int kc2 = 0; kc2 < 7; ++kc2) {
        LOADA(a, abase0, kc2)
        LOADB(b1, 2 * kc2 + 1)
        MFMA4(a, b0)
        LOADA(a, abase1, kc2)
        LOADB(b0, 2 * kc2 + 2)
        MFMA4(a, b1)
    }
    {   // tail kc2 = 7 (no b0 prefetch)
        LOADA(a, abase0, 7)
        LOADB(b1, 15)
        MFMA4(a, b0)
        LOADA(a, abase1, 7)
        MFMA4(a, b1)
    }

    // ---- epilogue: residual x read as bf16 from the LDS x-half
    #pragma unroll
    for (int rf = 0; rf < 4; ++rf) {
        const int rl0 = rf * 16 + (l >> 4) * 4;
        #pragma unroll
        for (int j = 0; j < 4; ++j) {
            int rl = rl0 + j;
            int r = row0 + rl;
            if (r >= NN) continue;
            int sw = (rl & 7) << 4;
            #pragma unroll
            for (int c = 0; c < 2; ++c) {
                int gg = w * 32 + c * 16 + (l & 15);
                unsigned short xb =
                    *reinterpret_cast<const unsigned short*>(&smem[rl * 1024 + ((512 + gg * 2) ^ sw)]);
                float xv = bf2f(xb);
                float c0 = acc[rf][c][j] + bias[gg];
                float c1 = acc[rf][c + 2][j] + bias[256 + gg];
                float arma = 0.5f * (fmaxf(c0, 0.f) + fmaxf(c1, 0.f));
                out[(size_t)r * FF + gg] = xv + fmaxf(arma, 0.f);
            }
        }
    }
}

extern "C" void kernel_launch(void* const* d_in, const int* in_sizes, int n_in,
                              void* d_out, int out_size, void* d_ws, size_t ws_size,
                              hipStream_t stream) {
    const float* x    = (const float*)d_in[0];
    const int*   ei   = (const int*)d_in[1];
    const float* wi   = (const float*)d_in[2];
    const float* wr   = (const float*)d_in[3];
    const float* bias = (const float*)d_in[4];
    float* out = (float*)d_out;

    // workspace (~2.6 MB)
    int*   deg     = (int*)d_ws;              // NN
    int*   off     = deg + NN;                // NN
    int*   cur     = off + NN;                // NN
    int*   csr_src = cur + NN;                // NE
    float* dinv    = (float*)(csr_src + NE);  // NN
    int*   bsum    = (int*)(dinv + NN);       // SCAN_B
    int*   boff    = bsum + SCAN_B;           // SCAN_B
    unsigned short* Bp = (unsigned short*)(boff + SCAN_B);   // 512*512 bf16 = 512 KB
    unsigned short* Ab = (unsigned short*)d_out;             // 50000 x 512 bf16 == d_out bytes

    hipMemsetAsync(deg, 0, NN * sizeof(int), stream);

    k_deg  <<<(NE + 255) / 256, 256, 0, stream>>>(ei, deg);
    k_scan1<<<SCAN_B, 256, 0, stream>>>(deg, bsum);
    k_scan2<<<1, 256, 0, stream>>>(bsum, boff);
    k_scan3<<<SCAN_B, 256, 0, stream>>>(deg, boff, off, cur, dinv);
    k_fill <<<(NE + 255) / 256, 256, 0, stream>>>(ei, cur, csr_src);
    k_xcvt <<<(NN * 64 + 255) / 256, 256, 0, stream>>>(x, Ab);
    k_bprep<<<128, 256, 0, stream>>>(wi, wr, Bp);
    k_agg  <<<(NN * 64 + 255) / 256, 256, 0, stream>>>(off, deg, csr_src, dinv, Ab);
    k_mm   <<<(NN + 63) / 64, 512, 0, stream>>>(Ab, Bp, bias, out);
}